// Round 3
// baseline (680.956 us; speedup 1.0000x reference)
//
#include <hip/hip_runtime.h>

constexpr int SEQ = 2048;
constexpr int HD  = 64;
constexpr int NH  = 8;
constexpr int NB  = 8;
constexpr int BM  = 64;
constexpr int BN  = 64;
constexpr int KST = 72;   // K/V LDS row stride (shorts): 144 B, b128-aligned, conflict-free reads
constexpr int PST = 68;   // P overlay row stride (shorts): 4*PST=136 dwords = 8 mod 32 -> conflict-free b16 writes
constexpr float INV_T = 0.125f;
constexpr float LOG2E = 1.4426950408889634f;

typedef __attribute__((ext_vector_type(8))) short bf16x8;
typedef __attribute__((ext_vector_type(8))) short s16x8;
typedef __attribute__((ext_vector_type(4))) short s16x4;
typedef __attribute__((ext_vector_type(4))) unsigned short us4;
typedef __attribute__((ext_vector_type(4))) float f32x4;

__device__ __forceinline__ short f2bf(float f) {
  unsigned u = __builtin_bit_cast(unsigned, f);
  u += 0x7fffu + ((u >> 16) & 1u);   // RNE
  return (short)(u >> 16);
}
__device__ __forceinline__ float bf2f(unsigned short s) {
  unsigned u = ((unsigned)s) << 16;
  return __builtin_bit_cast(float, u);
}
__device__ __forceinline__ float fast_exp2(float x) {
#if __has_builtin(__builtin_amdgcn_exp2f)
  return __builtin_amdgcn_exp2f(x);
#else
  return exp2f(x);
#endif
}

// ---------------- prep 1: K -> bf16 rows, V -> bf16 transposed [bh][d][j] ----------------
__global__ __launch_bounds__(256)
void prep_kv(const float* __restrict__ k, const float* __restrict__ v,
             unsigned short* __restrict__ kb, unsigned short* __restrict__ vt)
{
  __shared__ unsigned short t[HD * KST];
  const int bh = blockIdx.y, jt = blockIdx.x, tid = threadIdx.x;
  const size_t base = (size_t)bh * SEQ * HD + (size_t)jt * BN * HD;
  {
    const float* kp = k + base + 16 * tid;
    unsigned short ko[16];
    for (int e = 0; e < 4; ++e) {
      f32x4 x = *(const f32x4*)(kp + 4 * e);
      for (int c = 0; c < 4; ++c) ko[4 * e + c] = (unsigned short)f2bf(x[c]);
    }
    *(s16x8*)(kb + base + 16 * tid)     = *(const s16x8*)&ko[0];
    *(s16x8*)(kb + base + 16 * tid + 8) = *(const s16x8*)&ko[8];
  }
  {
    const float* vp = v + base + 16 * tid;
    const int j = tid >> 2, d0 = (tid & 3) * 16;
    for (int e = 0; e < 4; ++e) {
      f32x4 x = *(const f32x4*)(vp + 4 * e);
      for (int c = 0; c < 4; ++c) t[(d0 + 4 * e + c) * KST + j] = (unsigned short)f2bf(x[c]);
    }
  }
  __syncthreads();
  {
    const int d = tid >> 2, ch = tid & 3;
    const size_t ob = (size_t)bh * HD * SEQ + (size_t)d * SEQ + jt * BN + ch * 16;
    *(s16x8*)(vt + ob)     = *(const s16x8*)&t[d * KST + ch * 16];
    *(s16x8*)(vt + ob + 8) = *(const s16x8*)&t[d * KST + ch * 16 + 8];
  }
}

// ---------------- prep 2: mask*log2e -> bf16, C-layout order [jt][i][lq][sub] ----------------
__global__ __launch_bounds__(256)
void prep_mask(const float* __restrict__ mask, unsigned short* __restrict__ mp)
{
  const int w = blockIdx.x * 256 + threadIdx.x;   // 262,144 threads, 16 elems each
  const int W = w << 2;                            // base ushort4 index
  const int lq0 = W & 15;
  const int i   = (W >> 4) & 2047;
  const int jt  = W >> 15;
  const float* src = mask + (size_t)i * SEQ + jt * 64;
  unsigned short o[16];
  for (int c = 0; c < 4; ++c)
    for (int s = 0; s < 4; ++s)
      o[c * 4 + s] = (unsigned short)f2bf(src[s * 16 + lq0 + c] * LOG2E);
  *(s16x8*)(mp + (size_t)4 * W)     = *(const s16x8*)&o[0];
  *(s16x8*)(mp + (size_t)4 * W + 8) = *(const s16x8*)&o[8];
}

// ---------------- prep 3: pos -> bf16, C-layout order [h][jt][i][lq][sub] ----------------
__global__ __launch_bounds__(256)
void prep_pos(const float* __restrict__ pos, unsigned short* __restrict__ pp)
{
  const size_t w = (size_t)blockIdx.x * 256 + threadIdx.x;  // 2,097,152 threads
  const int W = (int)(w << 2);
  const int lq0 = W & 15;
  const int i   = (W >> 4) & 2047;
  const int jt  = (W >> 15) & 31;
  const int h   = (int)(w >> 18);
  const float* src = pos + ((size_t)h * SEQ + i) * SEQ + jt * 64;
  unsigned short o[16];
  for (int c = 0; c < 4; ++c)
    for (int s = 0; s < 4; ++s)
      o[c * 4 + s] = (unsigned short)f2bf(src[s * 16 + lq0 + c]);
  *(s16x8*)(pp + (size_t)4 * W)     = *(const s16x8*)&o[0];
  *(s16x8*)(pp + (size_t)4 * W + 8) = *(const s16x8*)&o[8];
}

// ---------------- main fused attention ----------------
__global__ __launch_bounds__(256, 8)
void attn_main(const float* __restrict__ q, const unsigned short* __restrict__ kb,
               const unsigned short* __restrict__ vt, const unsigned short* __restrict__ posp,
               const unsigned short* __restrict__ maskp, float* __restrict__ out)
{
  __shared__ unsigned short lds_k[BN * KST];   // K tile; P overlay (stride PST) after B3
  __shared__ unsigned short lds_v[HD * KST];   // V^T tile

  const int bh = blockIdx.y, h = bh & (NH - 1);
  const int i0 = blockIdx.x * BM;
  const int tid = threadIdx.x, wave = tid >> 6, lane = tid & 63;
  const int quad = lane >> 4, lq = lane & 15;

  // Q A-frags (scaled by 1/8 before rounding: exact exponent shift)
  bf16x8 aq[2];
  {
    const float* qp = q + ((size_t)bh * SEQ + i0 + wave * 16 + lq) * HD + quad * 8;
    for (int k0 = 0; k0 < 2; ++k0) {
      f32x4 x = *(const f32x4*)(qp + k0 * 32);
      f32x4 y = *(const f32x4*)(qp + k0 * 32 + 4);
      for (int c = 0; c < 4; ++c) {
        aq[k0][c]     = f2bf(x[c] * INV_T);
        aq[k0][4 + c] = f2bf(y[c] * INV_T);
      }
    }
  }

  f32x4 oacc[4];
  for (int d = 0; d < 4; ++d) oacc[d] = (f32x4){0.f, 0.f, 0.f, 0.f};
  float lrun[4] = {0.f, 0.f, 0.f, 0.f};

  const int lw = (tid >> 3) * KST + (tid & 7) * 8;
  const unsigned short* kgb = kb + (size_t)bh * SEQ * HD + 8 * tid;
  const unsigned short* vgb = vt + (size_t)bh * HD * SEQ + (tid >> 3) * SEQ + (tid & 7) * 8;
  const int irow = i0 + wave * 16 + quad * 4;  // + r
  const unsigned short* posb = posp + (((size_t)h * 65536 + irow) * 16 + lq) * 4;
  const unsigned short* mkb  = maskp + ((size_t)irow * 16 + lq) * 4;
  unsigned short* pwave = &lds_k[wave * (16 * PST)];   // 4*1088 = 4352 <= 4608, fits overlay

  // prefetch jt=0 staging tiles into registers
  s16x8 kx0 = *(const s16x8*)(kgb);
  s16x8 kx1 = *(const s16x8*)(kgb + 2048);
  s16x8 vx0 = *(const s16x8*)(vgb);
  s16x8 vx1 = *(const s16x8*)(vgb + 32 * SEQ);

  for (int jt = 0; jt < SEQ / BN; ++jt) {
    __syncthreads();                        // B1: prior iter's P/V readers done
    *(s16x8*)&lds_k[lw]            = kx0;
    *(s16x8*)&lds_k[lw + 32 * KST] = kx1;
    *(s16x8*)&lds_v[lw]            = vx0;
    *(s16x8*)&lds_v[lw + 32 * KST] = vx1;
    __syncthreads();                        // B2: staging visible

    // prefetch next tile (wraps on last iter; redundant but harmless)
    const int jn = (jt + 1) & 31;
    kx0 = *(const s16x8*)(kgb + jn * 4096);
    kx1 = *(const s16x8*)(kgb + jn * 4096 + 2048);
    vx0 = *(const s16x8*)(vgb + jn * 64);
    vx1 = *(const s16x8*)(vgb + jn * 64 + 32 * SEQ);

    // S = (Q/8) K^T
    f32x4 sa[4];
    for (int s = 0; s < 4; ++s) sa[s] = (f32x4){0.f, 0.f, 0.f, 0.f};
    for (int k0 = 0; k0 < 2; ++k0)
      for (int s = 0; s < 4; ++s) {
        bf16x8 bk = *(const bf16x8*)&lds_k[(s * 16 + lq) * KST + k0 * 32 + quad * 8];
        sa[s] = __builtin_amdgcn_mfma_f32_16x16x32_bf16(aq[k0], bk, sa[s], 0, 0, 0);
      }
    __syncthreads();                        // B3: K reads done; P overlay may write

    // softmax: p = exp2( maskb * (sa + posb) ); no max-tracking (bounded exponents)
    const unsigned short* pp = posb + jt * 131072;
    const unsigned short* mm = mkb  + jt * 131072;
    for (int r = 0; r < 4; ++r) {
      us4 pb4 = *(const us4*)(pp + r * 64);
      us4 mb4 = *(const us4*)(mm + r * 64);
      float ps = 0.f;
      for (int s = 0; s < 4; ++s) {
        float p = fast_exp2(bf2f(mb4[s]) * (sa[s][r] + bf2f(pb4[s])));
        unsigned pu = __builtin_bit_cast(unsigned, p);
        pwave[(quad * 4 + r) * PST + s * 16 + lq] = (unsigned short)(pu >> 16);
        ps += __builtin_bit_cast(float, pu & 0xffff0000u);   // sum the rounded p
      }
      lrun[r] += ps;                        // denominator deferred to epilogue
    }
    asm volatile("s_waitcnt lgkmcnt(0)" ::: "memory");  // wave-private P visibility

    // O += P V
    for (int k0 = 0; k0 < 2; ++k0) {
      const unsigned short* pr = &pwave[lq * PST + k0 * 32 + quad * 8];
      s16x4 lo = *(const s16x4*)pr;
      s16x4 hi = *(const s16x4*)(pr + 4);
      bf16x8 ap;
      for (int c = 0; c < 4; ++c) { ap[c] = lo[c]; ap[4 + c] = hi[c]; }
      for (int d = 0; d < 4; ++d) {
        bf16x8 bv = *(const bf16x8*)&lds_v[(d * 16 + lq) * KST + k0 * 32 + quad * 8];
        oacc[d] = __builtin_amdgcn_mfma_f32_16x16x32_bf16(ap, bv, oacc[d], 0, 0, 0);
      }
    }
  }

  // epilogue: single denominator reduction per row, then store
  for (int r = 0; r < 4; ++r) {
    float l = lrun[r];
    for (int off = 1; off < 16; off <<= 1) l += __shfl_xor(l, off);
    const float inv = 1.0f / l;
    float* orow = out + ((size_t)bh * SEQ + i0 + wave * 16 + quad * 4 + r) * HD + lq;
    for (int d = 0; d < 4; ++d) orow[d * 16] = oacc[d][r] * inv;
  }
}

// ---------------- fallback (R1 kernel, used if ws too small) ----------------
__global__ __launch_bounds__(256, 2)
void attn_fused(const float* __restrict__ q, const float* __restrict__ kk,
                const float* __restrict__ vv, const float* __restrict__ pos,
                const float* __restrict__ mask, float* __restrict__ out)
{
  __shared__ short lds_k[BN * KST];
  __shared__ short lds_v[HD * KST];
  __shared__ short lds_p[4][16 * KST];
  const int bh = blockIdx.y, h = bh & (NH - 1);
  const int i0 = blockIdx.x * BM;
  const int tid = threadIdx.x, wave = tid >> 6, lane = tid & 63;
  const int quad = lane >> 4, lq = lane & 15;
  bf16x8 aq[2];
  {
    const float* qp = q + ((size_t)bh * SEQ + i0 + wave * 16 + lq) * HD + quad * 8;
    for (int k0 = 0; k0 < 2; ++k0) {
      f32x4 x = *(const f32x4*)(qp + k0 * 32);
      f32x4 y = *(const f32x4*)(qp + k0 * 32 + 4);
      for (int j = 0; j < 4; ++j) { aq[k0][j] = f2bf(x[j] * INV_T); aq[k0][4 + j] = f2bf(y[j] * INV_T); }
    }
  }
  f32x4 oacc[4];
  for (int d = 0; d < 4; ++d) oacc[d] = (f32x4){0.f, 0.f, 0.f, 0.f};
  float mrun[4] = {-INFINITY, -INFINITY, -INFINITY, -INFINITY};
  float lrun[4] = {0.f, 0.f, 0.f, 0.f};
  const size_t kvbase = (size_t)bh * SEQ * HD;
  for (int jt = 0; jt < SEQ / BN; ++jt) {
    const int j0 = jt * BN;
    __syncthreads();
    for (int e = 0; e < 4; ++e) {
      int idx = e * 256 + tid, j = idx >> 4, d4 = (idx & 15) << 2;
      f32x4 kf = *(const f32x4*)(kk + kvbase + (size_t)(j0 + j) * HD + d4);
      s16x4 ks;
      for (int c = 0; c < 4; ++c) ks[c] = f2bf(kf[c]);
      *(s16x4*)&lds_k[j * KST + d4] = ks;
      f32x4 vf = *(const f32x4*)(vv + kvbase + (size_t)(j0 + j) * HD + d4);
      for (int c = 0; c < 4; ++c) lds_v[(d4 + c) * KST + j] = f2bf(vf[c]);
    }
    __syncthreads();
    float mk[4][4], pz[4][4];
    for (int r = 0; r < 4; ++r) {
      const int i = i0 + wave * 16 + quad * 4 + r;
      const float* mrow = mask + (size_t)i * SEQ + j0 + lq;
      const float* prow = pos + ((size_t)h * SEQ + i) * SEQ + j0 + lq;
      for (int s = 0; s < 4; ++s) { mk[r][s] = mrow[s * 16]; pz[r][s] = prow[s * 16]; }
    }
    f32x4 sa[4];
    for (int s = 0; s < 4; ++s) sa[s] = (f32x4){0.f, 0.f, 0.f, 0.f};
    for (int k0 = 0; k0 < 2; ++k0)
      for (int s = 0; s < 4; ++s) {
        bf16x8 bk = *(const bf16x8*)&lds_k[(s * 16 + lq) * KST + k0 * 32 + quad * 8];
        sa[s] = __builtin_amdgcn_mfma_f32_16x16x32_bf16(aq[k0], bk, sa[s], 0, 0, 0);
      }
    for (int r = 0; r < 4; ++r) {
      float s0 = mk[r][0] * (sa[0][r] + pz[r][0]);
      float s1 = mk[r][1] * (sa[1][r] + pz[r][1]);
      float s2 = mk[r][2] * (sa[2][r] + pz[r][2]);
      float s3 = mk[r][3] * (sa[3][r] + pz[r][3]);
      float rm = fmaxf(fmaxf(s0, s1), fmaxf(s2, s3));
      for (int off = 1; off < 16; off <<= 1) rm = fmaxf(rm, __shfl_xor(rm, off));
      float mn = fmaxf(mrun[r], rm);
      float al = __expf(mrun[r] - mn);
      mrun[r] = mn;
      short p0 = f2bf(__expf(s0 - mn)), p1 = f2bf(__expf(s1 - mn));
      short p2 = f2bf(__expf(s2 - mn)), p3 = f2bf(__expf(s3 - mn));
      float ps = bf2f((unsigned short)p0) + bf2f((unsigned short)p1) + bf2f((unsigned short)p2) + bf2f((unsigned short)p3);
      for (int off = 1; off < 16; off <<= 1) ps += __shfl_xor(ps, off);
      lrun[r] = lrun[r] * al + ps;
      for (int d = 0; d < 4; ++d) oacc[d][r] *= al;
      short* pr = &lds_p[wave][(quad * 4 + r) * KST + lq];
      pr[0] = p0; pr[16] = p1; pr[32] = p2; pr[48] = p3;
    }
    asm volatile("s_waitcnt lgkmcnt(0)" ::: "memory");
    for (int k0 = 0; k0 < 2; ++k0) {
      bf16x8 ap = *(const bf16x8*)&lds_p[wave][lq * KST + k0 * 32 + quad * 8];
      for (int d = 0; d < 4; ++d) {
        bf16x8 bv = *(const bf16x8*)&lds_v[(d * 16 + lq) * KST + k0 * 32 + quad * 8];
        oacc[d] = __builtin_amdgcn_mfma_f32_16x16x32_bf16(ap, bv, oacc[d], 0, 0, 0);
      }
    }
  }
  for (int r = 0; r < 4; ++r) {
    const int i = i0 + wave * 16 + quad * 4 + r;
    const float inv = 1.0f / lrun[r];
    float* orow = out + ((size_t)bh * SEQ + i) * HD + lq;
    for (int d = 0; d < 4; ++d) orow[d * 16] = oacc[d][r] * inv;
  }
}

extern "C" void kernel_launch(void* const* d_in, const int* in_sizes, int n_in,
                              void* d_out, int out_size, void* d_ws, size_t ws_size,
                              hipStream_t stream) {
  const float* q    = (const float*)d_in[0];
  const float* k    = (const float*)d_in[1];
  const float* v    = (const float*)d_in[2];
  const float* pos  = (const float*)d_in[3];
  const float* mask = (const float*)d_in[4];
  float* out = (float*)d_out;

  const size_t kb_bytes   = (size_t)NB * NH * SEQ * HD * 2;   // 16 MB
  const size_t posp_bytes = (size_t)NH * SEQ * SEQ * 2;       // 67 MB
  const size_t mask_bytes = (size_t)SEQ * SEQ * 2;            // 8.4 MB
  const size_t need = 2 * kb_bytes + posp_bytes + mask_bytes; // ~109 MB

  if (ws_size >= need) {
    unsigned short* kb = (unsigned short*)d_ws;
    unsigned short* vt = (unsigned short*)((char*)d_ws + kb_bytes);
    unsigned short* pp = (unsigned short*)((char*)d_ws + 2 * kb_bytes);
    unsigned short* mp = (unsigned short*)((char*)d_ws + 2 * kb_bytes + posp_bytes);
    prep_kv<<<dim3(SEQ / BN, NB * NH), dim3(256), 0, stream>>>(k, v, kb, vt);
    prep_mask<<<dim3(1024), dim3(256), 0, stream>>>(mask, mp);
    prep_pos<<<dim3(8192), dim3(256), 0, stream>>>(pos, pp);
    attn_main<<<dim3(SEQ / BM, NB * NH), dim3(256), 0, stream>>>(q, kb, vt, pp, mp, out);
  } else {
    attn_fused<<<dim3(SEQ / BM, NB * NH), dim3(256), 0, stream>>>(q, k, v, pos, mask, out);
  }
}